// Round 16
// baseline (87.003 us; speedup 1.0000x reference)
//
#include <hip/hip_runtime.h>
#include <hip/hip_bf16.h>
#include <hip/hip_cooperative_groups.h>

namespace cg = cooperative_groups;

#define N_CELLS  16384
#define N_SPOTS  4096
#define N_LABELS 512
#define MTHREADS 256     // block size (4 waves)
#define NBLK     1024    // grid: needs only 4 blocks/CU co-resident
#define NBUILD   8       // builder blocks
#define CPB      8       // cells per group
#define GROUPS   2       // groups per block -> 16 cells/block
#define NPAIR    (CPB/2) // packed-f32 cell pairs
#define TABLE    6144    // padded spot-table capacity (float2)

typedef float v2f __attribute__((ext_vector_type(2)));
typedef float v4f __attribute__((ext_vector_type(4)));   // NT-store-compatible

// Native exp2 (single v_exp_f32).
__device__ __forceinline__ float fast_exp2(float x) {
    float r;
    asm("v_exp_f32 %0, %1" : "=v"(r) : "v"(x));
    return r;
}

// log2(e)/2 : fold both 1/(2D) and log2(e) into the coordinate prescale
#define HALF_LOG2E 0.72134752044448170f

// Shared memory union: build-phase arrays (14.4 KB) overlay the main-phase
// transpose buffer (16 KB) -> 16 KB/block.
union SmemU {
    struct {
        int pre[N_LABELS];     // my-slice exclusive prefix per label
        int tot[N_LABELS];     // total counts per label
        int h2[128];           // histogram of counts
        int suf[128];          // suffix sums of h2
        int pcwA[32 * 4];      // per-(count,wave) label counts, labels 0..255
        int pcwB[32 * 4];      // labels 256..511
        int rlab[N_LABELS];    // rank -> label
        int rcnt[N_LABELS];    // rank -> count
        int slot[N_LABELS];    // label -> first table slot
        int kcur[N_LABELS];    // label -> next ordinal (this block)
        int wmax[8];           // per-chunk max count (= trip)
        int wbase[8];          // per-chunk table base
    } b;
    float tr[CPB * N_LABELS];  // 16 KB transpose buffer
};

// ---------------------------------------------------------------------------
// One chunk-phase of the K-loop: accumulate into acc[] over trip slots.
// ---------------------------------------------------------------------------
__device__ __forceinline__ void kphase(
    const v2f* __restrict__ seg, int trip,
    const v2f* zxn, const v2f* zyn, v2f* acc)
{
    if (trip <= 0) return;
    v2f xy = seg[0];
    for (int p = 0; p < trip; ++p) {
        const int pn = (p + 1 < trip) ? p + 1 : p;   // scalar select
        v2f nxt = seg[(size_t)pn * 64];              // depth-1 prefetch
        const v2f xx = (v2f){xy.x, xy.x};
        const v2f yy = (v2f){xy.y, xy.y};
        #pragma unroll
        for (int j = 0; j < NPAIR; ++j) {
            v2f dx  = xx + zxn[j];                              // v_pk_add
            v2f dy  = yy + zyn[j];                              // v_pk_add
            v2f m   = dy * dy;                                  // v_pk_mul
            v2f nd2 = __builtin_elementwise_fma(-dx, dx, -m);   // v_pk_fma
            v2f e   = (v2f){ fast_exp2(nd2.x), fast_exp2(nd2.y) };
            acc[j] += e;                                        // v_pk_add
        }
        xy = nxt;
    }
}

// ---------------------------------------------------------------------------
// SINGLE fused cooperative kernel: blocks 0-7 build the count-ranked padded
// spot table + meta, grid.sync(), then all blocks run the main pass
// (2 groups x 8 cells). Eliminates the ~13us two-kernel dispatch/boundary
// overhead measured in rounds 5-12 (single-node graph overhead = 0.2us, R6).
// ---------------------------------------------------------------------------
__global__ __launch_bounds__(MTHREADS, 4) void diffusion_fused_kernel(
    const float* __restrict__ z, const float* __restrict__ dconst,
    const float* __restrict__ ex, const float* __restrict__ ey,
    const int* __restrict__ labels,
    float2* __restrict__ table, int* __restrict__ meta,
    float* __restrict__ out)
{
    __shared__ SmemU smem;

    const int t = threadIdx.x;
    const int lane = t & 63, w = t >> 6;   // 4 waves
    const int bid = blockIdx.x;

    // ------------------------- build phase (blocks 0-7) -------------------
    if (bid < NBUILD) {
        auto& bs = smem.b;
        const int b = bid;

        bs.pre[t] = 0; bs.pre[t + 256] = 0;
        bs.tot[t] = 0; bs.tot[t + 256] = 0;
        if (t < 128) bs.h2[t] = 0;
        __syncthreads();

        // exclusive prefix of my slice: histogram spots [0, 512b)
        for (int i = t; i < 512 * b; i += MTHREADS)
            atomicAdd(&bs.pre[labels[i]], 1);
        __syncthreads();
        bs.tot[t] = bs.pre[t]; bs.tot[t + 256] = bs.pre[t + 256];
        __syncthreads();
        // continue into totals with spots [512b, 4096)
        for (int i = 512 * b + t; i < N_SPOTS; i += MTHREADS)
            atomicAdd(&bs.tot[labels[i]], 1);
        __syncthreads();

        const int mycA = bs.tot[t], mycB = bs.tot[t + 256];
        atomicAdd(&bs.h2[mycA < 127 ? mycA : 127], 1);
        atomicAdd(&bs.h2[mycB < 127 ? mycB : 127], 1);
        __syncthreads();

        // suffix-scan h2: suf[v] = #labels with count >= v
        if (t < 128) bs.suf[t] = bs.h2[t];
        __syncthreads();
        for (int off = 1; off < 128; off <<= 1) {
            int add = (t < 128 && t + off < 128) ? bs.suf[t + off] : 0;
            __syncthreads();
            if (t < 128) bs.suf[t] += add;
            __syncthreads();
        }

        // ballot rank in two passes: pass A = labels [0,256), B = [256,512)
        int posAw = 0, posBw = 0;
        for (int v = 0; v < 32; ++v) {
            unsigned long long mA = __ballot(mycA == v);
            if (mycA == v) posAw = __popcll(mA & ((1ull << lane) - 1ull));
            if (lane == 0) bs.pcwA[v * 4 + w] = __popcll(mA);
            unsigned long long mB = __ballot(mycB == v);
            if (mycB == v) posBw = __popcll(mB & ((1ull << lane) - 1ull));
            if (lane == 0) bs.pcwB[v * 4 + w] = __popcll(mB);
        }
        __syncthreads();
        int posA, posB;
        if (mycA < 32) {
            posA = posAw;
            for (int w2 = 0; w2 < w; ++w2) posA += bs.pcwA[mycA * 4 + w2];
        } else {  // astronomically rare; deterministic fallback
            posA = 0;
            for (int j = 0; j < t; ++j) posA += (bs.tot[j] == mycA) ? 1 : 0;
        }
        if (mycB < 32) {
            posB = posBw;
            for (int w2 = 0; w2 < 4; ++w2) posB += bs.pcwA[mycB * 4 + w2];
            for (int w2 = 0; w2 < w; ++w2) posB += bs.pcwB[mycB * 4 + w2];
        } else {
            posB = 0;
            for (int j = 0; j < t + 256; ++j) posB += (bs.tot[j] == mycB) ? 1 : 0;
        }
        const int rA = ((mycA < 127) ? bs.suf[mycA + 1] : 0) + posA;
        const int rB = ((mycB < 127) ? bs.suf[mycB + 1] : 0) + posB;
        bs.rlab[rA] = t;       bs.rcnt[rA] = mycA;
        bs.rlab[rB] = t + 256; bs.rcnt[rB] = mycB;
        __syncthreads();

        // per-chunk (64 ranks) max via wave shuffle: wave w covers chunk w
        // (ranks=t) and chunk w+4 (ranks=t+256)
        {
            int v0 = bs.rcnt[t], v1 = bs.rcnt[t + 256];
            #pragma unroll
            for (int off = 32; off; off >>= 1) {
                int o0 = __shfl_xor(v0, off); v0 = v0 > o0 ? v0 : o0;
                int o1 = __shfl_xor(v1, off); v1 = v1 > o1 ? v1 : o1;
            }
            if (lane == 0) { bs.wmax[w] = v0; bs.wmax[w + 4] = v1; }
        }
        __syncthreads();
        if (t == 0) {
            int pb = 0;
            #pragma unroll
            for (int c = 0; c < 8; ++c) { bs.wbase[c] = 64 * pb; pb += bs.wmax[c]; }
        }
        __syncthreads();

        bs.slot[t]       = bs.wbase[rA >> 6] + (rA & 63);
        bs.kcur[t]       = bs.pre[t];
        bs.slot[t + 256] = bs.wbase[rB >> 6] + (rB & 63);
        bs.kcur[t + 256] = bs.pre[t + 256];
        __syncthreads();

        const float Dv = dconst[0];
        const float scb = sqrtf(HALF_LOG2E / Dv);

        // emit my slice (coalesced ex/ey reads, scattered 8B table writes)
        for (int i = 512 * b + t; i < 512 * (b + 1); i += MTHREADS) {
            int l = labels[i];
            int k = atomicAdd(&bs.kcur[l], 1);
            table[bs.slot[l] + k * 64] = make_float2(ex[i] * scb, ey[i] * scb);
        }
        // fill pad slots of ranks [64b, 64b+64)
        {
            const int q    = 64 * b + (t & 63);
            const int trip = bs.wmax[b];
            const int base = bs.wbase[b];
            for (int k = bs.rcnt[q] + (t >> 6); k < trip; k += 4)
                table[base + k * 64 + (t & 63)] = make_float2(1e8f, 0.0f);
        }
        if (b == 0) {
            for (int m = t; m < N_LABELS; m += MTHREADS) {
                meta[m]        = bs.wbase[m >> 6];
                meta[512 + m]  = bs.wmax[m >> 6];
                meta[1024 + m] = bs.rlab[m];
                meta[1536 + m] = bs.rcnt[m];
            }
        }
        __threadfence();   // device-scope release before grid sync
    }

    cg::this_grid().sync();

    // ------------------------- main phase (all blocks) ---------------------
    const int p  = (w + bid) & 3;           // rotated pair assignment
    const int cA = p, cB = 7 - p;
    const int uA = cA * 64 + lane;
    const int uB = cB * 64 + lane;

    const int wbaseA = __builtin_amdgcn_readfirstlane(meta[uA]);
    const int tripA  = __builtin_amdgcn_readfirstlane(meta[512 + uA]);
    const int labA   = meta[1024 + uA];
    const float cntA = (float)meta[1536 + uA];
    const int wbaseB = __builtin_amdgcn_readfirstlane(meta[uB]);
    const int tripB  = __builtin_amdgcn_readfirstlane(meta[512 + uB]);
    const int labB   = meta[1024 + uB];
    const float cntB = (float)meta[1536 + uB];

    const float D     = dconst[0];
    const float sc    = sqrtf(HALF_LOG2E / D);
    const float norm  = 1.0f / (6.28318530717958647f * D);
    const float baseA = cntA * 1e-12f;      // hoisted UNDERFLOW_NU
    const float baseB = cntB * 1e-12f;

    const v2f* tab = (const v2f*)table;
    float* tr = smem.tr;

    #pragma unroll
    for (int g = 0; g < GROUPS; ++g) {
        __syncthreads();   // tr WAR guard (vs build smem use / prior group)

        const int cell0 = bid * (CPB * GROUPS) + g * CPB;
        v2f zxn[NPAIR], zyn[NPAIR], accA[NPAIR], accB[NPAIR];
        #pragma unroll
        for (int j = 0; j < NPAIR; ++j) {
            zxn[j] = (v2f){ -z[2 * (cell0 + 2 * j)]     * sc,
                            -z[2 * (cell0 + 2 * j + 1)] * sc };
            zyn[j] = (v2f){ -z[2 * (cell0 + 2 * j) + 1]     * sc,
                            -z[2 * (cell0 + 2 * j + 1) + 1] * sc };
            accA[j] = (v2f){0.f, 0.f};
            accB[j] = (v2f){0.f, 0.f};
        }

        kphase(tab + wbaseA + lane, tripA, zxn, zyn, accA);
        kphase(tab + wbaseB + lane, tripB, zxn, zyn, accB);

        // transpose in LDS so global stores are coalesced
        #pragma unroll
        for (int j = 0; j < NPAIR; ++j) {
            tr[(2 * j)     * N_LABELS + labA] = fmaf(accA[j].x, norm, baseA);
            tr[(2 * j + 1) * N_LABELS + labA] = fmaf(accA[j].y, norm, baseA);
            tr[(2 * j)     * N_LABELS + labB] = fmaf(accB[j].x, norm, baseB);
            tr[(2 * j + 1) * N_LABELS + labB] = fmaf(accB[j].y, norm, baseB);
        }
        __syncthreads();

        const v4f* tr4 = (const v4f*)tr;
        v4f* out4 = (v4f*)(out + (size_t)cell0 * N_LABELS);
        #pragma unroll
        for (int rr = 0; rr < CPB * N_LABELS / 4 / MTHREADS; ++rr)   // 4 iters
            __builtin_nontemporal_store(tr4[t + rr * MTHREADS],
                                        &out4[t + rr * MTHREADS]);
    }
}

// ---------------------------------------------------------------------------
extern "C" void kernel_launch(void* const* d_in, const int* in_sizes, int n_in,
                              void* d_out, int out_size, void* d_ws, size_t ws_size,
                              hipStream_t stream)
{
    const float* z      = (const float*)d_in[0];  // (16384, 2)
    const float* dconst = (const float*)d_in[1];  // scalar
    const float* ex     = (const float*)d_in[2];  // (4096,)
    const float* ey     = (const float*)d_in[3];  // (4096,)
    const int*   labels = (const int*)d_in[4];    // (4096,)
    float*       out    = (float*)d_out;          // (16384, 512)

    float2* table = (float2*)d_ws;                                        // 48 KB
    int*    meta  = (int*)((char*)d_ws + (size_t)TABLE * sizeof(float2)); // 8 KB

    void* kargs[] = { (void*)&z, (void*)&dconst, (void*)&ex, (void*)&ey,
                      (void*)&labels, (void*)&table, (void*)&meta, (void*)&out };

    hipError_t err = hipLaunchCooperativeKernel(
        (const void*)diffusion_fused_kernel,
        dim3(NBLK), dim3(MTHREADS), kargs, 0, stream);
    (void)err;
}